// Round 1
// baseline (90.776 us; speedup 1.0000x reference)
//
#include <hip/hip_runtime.h>
#include <hip/hip_bf16.h>

#define D 128
#define LPE 16              // lanes per edge (each lane owns 8 dims)
#define BLOCK 256           // 4 waves, 16 edges per block iteration

__global__ __launch_bounds__(BLOCK) void edge_score_kernel(
    const float* __restrict__ h,
    const int*   __restrict__ src,
    const int*   __restrict__ dst,
    const float* __restrict__ W_w,   // [1, 2*D] : first D = Wu, next D = Wv
    const float* __restrict__ W_b,   // [1]
    float*       __restrict__ out,   // [n_edges]
    int n_edges)
{
    const int lane = threadIdx.x & (LPE - 1);

    // Preload this lane's 8 weights for Wu and Wv (once per thread).
    float wu[8], wv[8];
#pragma unroll
    for (int j = 0; j < 8; ++j) {
        wu[j] = W_w[lane * 8 + j];
        wv[j] = W_w[D + lane * 8 + j];
    }
    const float bias = W_b[0];

    const int tid     = blockIdx.x * BLOCK + threadIdx.x;
    const int egroup  = tid >> 4;                       // edge handled by this 16-lane group
    const int estride = (gridDim.x * BLOCK) >> 4;

    for (int e = egroup; e < n_edges; e += estride) {
        const int u = src[e];
        const int v = dst[e];

        const float4* hu = reinterpret_cast<const float4*>(h + (size_t)u * D) + lane * 2;
        const float4* hv = reinterpret_cast<const float4*>(h + (size_t)v * D) + lane * 2;

        float4 a0 = hu[0];
        float4 a1 = hu[1];
        float4 c0 = hv[0];
        float4 c1 = hv[1];

        float s = a0.x * wu[0] + a0.y * wu[1] + a0.z * wu[2] + a0.w * wu[3]
                + a1.x * wu[4] + a1.y * wu[5] + a1.z * wu[6] + a1.w * wu[7]
                + c0.x * wv[0] + c0.y * wv[1] + c0.z * wv[2] + c0.w * wv[3]
                + c1.x * wv[4] + c1.y * wv[5] + c1.z * wv[6] + c1.w * wv[7];

        // Reduce across the 16-lane group.
        s += __shfl_xor(s, 1, 64);
        s += __shfl_xor(s, 2, 64);
        s += __shfl_xor(s, 4, 64);
        s += __shfl_xor(s, 8, 64);

        if (lane == 0) out[e] = s + bias;
    }
}

extern "C" void kernel_launch(void* const* d_in, const int* in_sizes, int n_in,
                              void* d_out, int out_size, void* d_ws, size_t ws_size,
                              hipStream_t stream)
{
    const float* h   = (const float*)d_in[0];
    const int*   src = (const int*)d_in[1];
    const int*   dst = (const int*)d_in[2];
    const float* W_w = (const float*)d_in[3];
    const float* W_b = (const float*)d_in[4];
    float*       out = (float*)d_out;

    const int n_edges = in_sizes[1];   // 625000

    // Memory-bound: cap grid and grid-stride (Guideline 11). 16 edges/block.
    int blocks_needed = (n_edges + (BLOCK / LPE) - 1) / (BLOCK / LPE);
    int grid = blocks_needed < 2048 ? blocks_needed : 2048;

    edge_score_kernel<<<grid, BLOCK, 0, stream>>>(h, src, dst, W_w, W_b, out, n_edges);
}

// Round 2
// 22.092 us; speedup vs baseline: 4.1090x; 4.1090x over previous
//
#include <hip/hip_runtime.h>
#include <hip/hip_bf16.h>

#define D 128
#define LPE 16              // lanes per node (each lane owns 8 dims)
#define BLOCK 256

// Phase 1: per-node projections pu[n] = dot(h[n], Wu), pv[n] = dot(h[n], Wv).
// Sequential, fully-coalesced read of h (51.2 MB, exactly once).
__global__ __launch_bounds__(BLOCK) void node_proj_kernel(
    const float* __restrict__ h,
    const float* __restrict__ W_w,   // [2*D] : first D = Wu, next D = Wv
    float*       __restrict__ pu,    // [n_nodes]
    float*       __restrict__ pv,    // [n_nodes]
    int n_nodes)
{
    const int lane = threadIdx.x & (LPE - 1);

    float wu[8], wv[8];
#pragma unroll
    for (int j = 0; j < 8; ++j) {
        wu[j] = W_w[lane * 8 + j];
        wv[j] = W_w[D + lane * 8 + j];
    }

    const int tid    = blockIdx.x * BLOCK + threadIdx.x;
    const int group  = tid >> 4;
    const int stride = (gridDim.x * BLOCK) >> 4;

    for (int n = group; n < n_nodes; n += stride) {
        const float4* hp = reinterpret_cast<const float4*>(h + (size_t)n * D) + lane * 2;
        float4 a0 = hp[0];
        float4 a1 = hp[1];

        float su = a0.x * wu[0] + a0.y * wu[1] + a0.z * wu[2] + a0.w * wu[3]
                 + a1.x * wu[4] + a1.y * wu[5] + a1.z * wu[6] + a1.w * wu[7];
        float sv = a0.x * wv[0] + a0.y * wv[1] + a0.z * wv[2] + a0.w * wv[3]
                 + a1.x * wv[4] + a1.y * wv[5] + a1.z * wv[6] + a1.w * wv[7];

#pragma unroll
        for (int off = 1; off < LPE; off <<= 1) {
            su += __shfl_xor(su, off, 64);
            sv += __shfl_xor(sv, off, 64);
        }

        if (lane == 0) {
            pu[n] = su;
            pv[n] = sv;
        }
    }
}

// Phase 2: out[e] = pu[src[e]] + pv[dst[e]] + b. pu/pv are 400 KB each ->
// resident in every XCD's 4 MB L2; gathers are cache hits.
__global__ __launch_bounds__(BLOCK) void edge_score_kernel(
    const float* __restrict__ pu,
    const float* __restrict__ pv,
    const int*   __restrict__ src,
    const int*   __restrict__ dst,
    const float* __restrict__ W_b,
    float*       __restrict__ out,
    int n_edges)
{
    const float bias = W_b[0];
    const int e = blockIdx.x * BLOCK + threadIdx.x;
    if (e < n_edges) {
        out[e] = pu[src[e]] + pv[dst[e]] + bias;
    }
}

extern "C" void kernel_launch(void* const* d_in, const int* in_sizes, int n_in,
                              void* d_out, int out_size, void* d_ws, size_t ws_size,
                              hipStream_t stream)
{
    const float* h   = (const float*)d_in[0];
    const int*   src = (const int*)d_in[1];
    const int*   dst = (const int*)d_in[2];
    const float* W_w = (const float*)d_in[3];
    const float* W_b = (const float*)d_in[4];
    float*       out = (float*)d_out;

    const int n_nodes = in_sizes[0] / D;   // 100000
    const int n_edges = in_sizes[1];       // 625000

    float* pu = (float*)d_ws;
    float* pv = pu + n_nodes;

    // Phase 1: grid-stride, capped grid (memory-bound streaming).
    int blocks1 = (n_nodes + (BLOCK / LPE) - 1) / (BLOCK / LPE);
    if (blocks1 > 2048) blocks1 = 2048;
    node_proj_kernel<<<blocks1, BLOCK, 0, stream>>>(h, W_w, pu, pv, n_nodes);

    // Phase 2: one thread per edge (stream-ordered after phase 1).
    int blocks2 = (n_edges + BLOCK - 1) / BLOCK;
    edge_score_kernel<<<blocks2, BLOCK, 0, stream>>>(pu, pv, src, dst, W_b, out, n_edges);
}

// Round 3
// 21.903 us; speedup vs baseline: 4.1444x; 1.0086x over previous
//
#include <hip/hip_runtime.h>
#include <hip/hip_bf16.h>

#define D 128
#define LPE 16              // lanes per node-group (each lane owns 8 dims)
#define BLOCK 256
#define NPG 2               // nodes per 16-lane group (ILP: 64 B/lane in flight)

// Phase 1: pu[n] = dot(h[n], Wu), pv[n] = dot(h[n], Wv).
// Reads h (51.2 MB) exactly once, fully coalesced. BW-bound floor ~8 us.
__global__ __launch_bounds__(BLOCK) void node_proj_kernel(
    const float* __restrict__ h,
    const float* __restrict__ W_w,   // [2*D] : first D = Wu, next D = Wv
    float*       __restrict__ pu,    // [n_nodes]
    float*       __restrict__ pv,    // [n_nodes]
    int n_nodes)
{
    const int lane = threadIdx.x & (LPE - 1);

    float wu[8], wv[8];
#pragma unroll
    for (int j = 0; j < 8; ++j) {
        wu[j] = W_w[lane * 8 + j];
        wv[j] = W_w[D + lane * 8 + j];
    }

    const int group = (blockIdx.x * BLOCK + threadIdx.x) >> 4;
    const int n0 = group * NPG;
    if (n0 >= n_nodes) return;

    // Issue all loads first (2 nodes x 2 float4 = 64 B/lane outstanding).
    const float4* hp0 = reinterpret_cast<const float4*>(h + (size_t)n0 * D) + lane * 2;
    const bool has1 = (n0 + 1) < n_nodes;
    const float4* hp1 = reinterpret_cast<const float4*>(h + (size_t)(has1 ? n0 + 1 : n0) * D) + lane * 2;

    float4 a0 = hp0[0];
    float4 a1 = hp0[1];
    float4 b0 = hp1[0];
    float4 b1 = hp1[1];

    float su0 = a0.x * wu[0] + a0.y * wu[1] + a0.z * wu[2] + a0.w * wu[3]
              + a1.x * wu[4] + a1.y * wu[5] + a1.z * wu[6] + a1.w * wu[7];
    float sv0 = a0.x * wv[0] + a0.y * wv[1] + a0.z * wv[2] + a0.w * wv[3]
              + a1.x * wv[4] + a1.y * wv[5] + a1.z * wv[6] + a1.w * wv[7];
    float su1 = b0.x * wu[0] + b0.y * wu[1] + b0.z * wu[2] + b0.w * wu[3]
              + b1.x * wu[4] + b1.y * wu[5] + b1.z * wu[6] + b1.w * wu[7];
    float sv1 = b0.x * wv[0] + b0.y * wv[1] + b0.z * wv[2] + b0.w * wv[3]
              + b1.x * wv[4] + b1.y * wv[5] + b1.z * wv[6] + b1.w * wv[7];

#pragma unroll
    for (int off = 1; off < LPE; off <<= 1) {
        su0 += __shfl_xor(su0, off, 64);
        sv0 += __shfl_xor(sv0, off, 64);
        su1 += __shfl_xor(su1, off, 64);
        sv1 += __shfl_xor(sv1, off, 64);
    }

    if (lane == 0) {
        pu[n0] = su0;
        pv[n0] = sv0;
        if (has1) {
            pu[n0 + 1] = su1;
            pv[n0 + 1] = sv1;
        }
    }
}

// Phase 2: out[e] = pu[src[e]] + pv[dst[e]] + b. 4 edges/thread.
// pu/pv (800 KB total) are L2-resident; idx reads + out writes coalesced.
__global__ __launch_bounds__(BLOCK) void edge_score_kernel(
    const float* __restrict__ pu,
    const float* __restrict__ pv,
    const int*   __restrict__ src,
    const int*   __restrict__ dst,
    const float* __restrict__ W_b,
    float*       __restrict__ out,
    int n_edges)
{
    const float bias = W_b[0];
    const int n_quads = n_edges >> 2;
    const int q = blockIdx.x * BLOCK + threadIdx.x;

    if (q < n_quads) {
        int4 s = reinterpret_cast<const int4*>(src)[q];
        int4 d = reinterpret_cast<const int4*>(dst)[q];
        float4 r;
        r.x = pu[s.x] + pv[d.x] + bias;
        r.y = pu[s.y] + pv[d.y] + bias;
        r.z = pu[s.z] + pv[d.z] + bias;
        r.w = pu[s.w] + pv[d.w] + bias;
        reinterpret_cast<float4*>(out)[q] = r;
    }

    // Defensive tail (n_edges % 4 != 0); no-op for 625000.
    if (q == 0) {
        for (int e = n_quads << 2; e < n_edges; ++e)
            out[e] = pu[src[e]] + pv[dst[e]] + bias;
    }
}

extern "C" void kernel_launch(void* const* d_in, const int* in_sizes, int n_in,
                              void* d_out, int out_size, void* d_ws, size_t ws_size,
                              hipStream_t stream)
{
    const float* h   = (const float*)d_in[0];
    const int*   src = (const int*)d_in[1];
    const int*   dst = (const int*)d_in[2];
    const float* W_w = (const float*)d_in[3];
    const float* W_b = (const float*)d_in[4];
    float*       out = (float*)d_out;

    const int n_nodes = in_sizes[0] / D;   // 100000
    const int n_edges = in_sizes[1];       // 625000

    float* pu = (float*)d_ws;
    float* pv = pu + n_nodes;

    // Phase 1: exact grid, 2 nodes per 16-lane group.
    const int groups1 = (n_nodes + NPG - 1) / NPG;                 // 50000
    const int blocks1 = (groups1 * LPE + BLOCK - 1) / BLOCK;       // 3125
    node_proj_kernel<<<blocks1, BLOCK, 0, stream>>>(h, W_w, pu, pv, n_nodes);

    // Phase 2: 4 edges per thread.
    const int n_quads = n_edges >> 2;                              // 156250
    const int blocks2 = (n_quads + BLOCK - 1) / BLOCK;             // 611
    edge_score_kernel<<<blocks2, BLOCK, 0, stream>>>(pu, pv, src, dst, W_b, out, n_edges);
}